// Round 17
// baseline (154.034 us; speedup 1.0000x reference)
//
#include <hip/hip_runtime.h>

typedef unsigned short u16;
typedef __attribute__((ext_vector_type(4))) unsigned short u16x4;
typedef __attribute__((ext_vector_type(8))) unsigned short u16x8;
typedef __attribute__((ext_vector_type(8))) short s16x8;
typedef __attribute__((ext_vector_type(4))) float f32x4;
typedef __attribute__((ext_vector_type(16))) float f32x16;
typedef __attribute__((ext_vector_type(4))) unsigned int u32x4;

#define LOG2E 1.4426950408889634f

__device__ __forceinline__ u16 f2bf(float f) {
    return __builtin_bit_cast(unsigned short, static_cast<__bf16>(f));
}

__device__ __forceinline__ float bf2f(u16 v) {
    return __builtin_bit_cast(float, (unsigned)v << 16);
}

__device__ __forceinline__ float fexp2(float x) {
#if __has_builtin(__builtin_amdgcn_exp2f)
    return __builtin_amdgcn_exp2f(x);
#else
    return exp2f(x);
#endif
}

__device__ __forceinline__ s16x8 ld_frag(const u16* p) {
    return __builtin_bit_cast(s16x8, *reinterpret_cast<const u16x8*>(p));
}

__device__ __forceinline__ f32x4 mfma16(s16x8 a, s16x8 b, f32x4 c) {
    return __builtin_amdgcn_mfma_f32_16x16x32_bf16(a, b, c, 0, 0, 0);
}

__device__ __forceinline__ f32x16 mfma32(s16x8 a, s16x8 b, f32x16 c) {
    return __builtin_amdgcn_mfma_f32_32x32x16_bf16(a, b, c, 0, 0, 0);
}

__device__ __forceinline__ unsigned cvt_pk_bf16(float lo, float hi2) {
    unsigned r;
    asm("v_cvt_pk_bf16_f32 %0, %1, %2" : "=v"(r) : "v"(lo), "v"(hi2));
    return r;
}

__device__ __forceinline__ void plane32_swap(unsigned& x, unsigned& y) {
#if __has_builtin(__builtin_amdgcn_permlane32_swap)
    auto r = __builtin_amdgcn_permlane32_swap(x, y, false, false);
    x = r[0];
    y = r[1];
#else
    asm("v_permlane32_swap_b32 %0, %1" : "+v"(x), "+v"(y));
#endif
}

// async global->LDS, 16B per lane; LDS dest = wave-uniform base + lane*16
__device__ __forceinline__ void async16(const u16* g, u16* lds) {
    __builtin_amdgcn_global_load_lds(
        (__attribute__((address_space(1))) void*)const_cast<u16*>(g),
        (__attribute__((address_space(3))) void*)lds, 16, 0, 0);
}

// ---------------- fused prep: f32->bf16 cvt (x, ctx) + 4 weight transposes ----------------
// blocks [0,5120): cvt; blocks [5120,6656): wtrans (384 per weight, kx in [0,24), ny in [0,16))
__global__ __launch_bounds__(256) void prep_kernel(
    const float* __restrict__ x, const float* __restrict__ ctx, const float* __restrict__ Wq,
    const float* __restrict__ Wk, const float* __restrict__ Wv, const float* __restrict__ Wo,
    u16* __restrict__ xb, u16* __restrict__ cb, u16* __restrict__ Wqt, u16* __restrict__ Wkt,
    u16* __restrict__ Wvt, u16* __restrict__ Wot) {
    __shared__ float t[32][33];
    const int bidx = blockIdx.x;
    const int tid = threadIdx.x;
    if (bidx < 5120) {
        int i = bidx * 256 + tid;  // 1,310,720 total (exact)
        const float* in;
        u16* out;
        int idx;
        if (i < 524288) {
            in = x; out = xb; idx = i;
        } else {
            in = ctx; out = cb; idx = i - 524288;
        }
        const f32x4* p = (const f32x4*)in + ((size_t)idx << 1);
        f32x4 a = p[0], c = p[1];
        u16x8 v;
        v[0] = f2bf(a[0]); v[1] = f2bf(a[1]); v[2] = f2bf(a[2]); v[3] = f2bf(a[3]);
        v[4] = f2bf(c[0]); v[5] = f2bf(c[1]); v[6] = f2bf(c[2]); v[7] = f2bf(c[3]);
        *((u16x8*)out + idx) = v;
    } else {
        const int zb = bidx - 5120;      // 0..1535
        const int z = zb / 384;
        const int rem = zb - z * 384;
        const int kx = rem % 24, ny = rem / 24;
        const float* W;
        u16* Wt;
        int Kd;
        float scale;
        switch (z) {
            case 0: W = Wq; Wt = Wqt; Kd = 512; scale = 1.0f; break;
            case 1: W = Wk; Wt = Wkt; Kd = 768; scale = 0.125f * LOG2E; break;
            case 2: W = Wv; Wt = Wvt; Kd = 768; scale = 1.0f; break;
            default: W = Wo; Wt = Wot; Kd = 512; scale = 1.0f; break;
        }
        const int k0 = kx << 5, n0 = ny << 5;
        if (k0 >= Kd) return;
        const int tx = tid & 31, ty = tid >> 5;
#pragma unroll
        for (int i = 0; i < 32; i += 8)
            t[ty + i][tx] = W[(size_t)(k0 + ty + i) * 512 + n0 + tx] * scale;
        __syncthreads();
#pragma unroll
        for (int i = 0; i < 32; i += 8)
            Wt[(size_t)(n0 + ty + i) * Kd + k0 + tx] = f2bf(t[tx][ty + i]);
    }
}

// ---------------- 128x128 bf16 GEMM body: C = A[M][K] @ Bt[512][K]^T ----------------
// MODE 0: bf16 std [m][512]; MODE 1: K fragment-pack; MODE 2: V fragment-pack;
// MODE 3: f32 std + bias.
// MODE 1/2 epilogue: LDS repack (into dead Ab) -> 8 coalesced 4KB chunk copies.
template <int MODE>
__device__ __forceinline__ void gemm_body(u16* __restrict__ Ab, u16* __restrict__ Bb,
                                          const u16* __restrict__ A, const u16* __restrict__ Bt,
                                          void* __restrict__ Cv, const float* __restrict__ bias,
                                          int K) {
    const int tid = threadIdx.x;
    const int w = tid >> 6, l = tid & 63;
    const int lg = l >> 4, lq = l & 15;
    const int wm = w >> 1, wn = w & 1;
    const int bm = blockIdx.y, bn = blockIdx.x;
    const int KT = K >> 6;

    f32x4 acc[4][4];
#pragma unroll
    for (int i = 0; i < 4; i++)
#pragma unroll
        for (int j = 0; j < 4; j++) acc[i][j] = (f32x4){0.f, 0.f, 0.f, 0.f};

    const u16* Ag0 = A + (size_t)bm * 128 * K;
    const u16* Bg0 = Bt + (size_t)bn * 128 * K;
    const int srow = l >> 3, scol = (l & 7) << 3;

    auto stage = [&](int kt, int buf) {
#pragma unroll
        for (int i = 0; i < 4; i++) {
            const int c = (w << 2) + i;
            const int row = (c << 3) + srow;
            async16(Ag0 + (size_t)row * K + kt * 64 + scol, Ab + (buf << 13) + (c << 9));
            async16(Bg0 + (size_t)row * K + kt * 64 + scol, Bb + (buf << 13) + (c << 9));
        }
    };

    stage(0, 0);
    for (int kt = 0; kt < KT; ++kt) {
        __syncthreads();
        if (kt + 1 < KT) stage(kt + 1, (kt + 1) & 1);
        const u16* As = Ab + ((kt & 1) << 13);
        const u16* Bs = Bb + ((kt & 1) << 13);
#pragma unroll
        for (int s = 0; s < 2; s++) {
            s16x8 af[4], bfr[4];
#pragma unroll
            for (int mt = 0; mt < 4; mt++)
                af[mt] = ld_frag(As + ((wm << 6) + (mt << 4) + lq) * 64 + (s << 5) + (lg << 3));
#pragma unroll
            for (int nt = 0; nt < 4; nt++)
                bfr[nt] = ld_frag(Bs + ((wn << 6) + (nt << 4) + lq) * 64 + (s << 5) + (lg << 3));
#pragma unroll
            for (int mt = 0; mt < 4; mt++)
#pragma unroll
                for (int nt = 0; nt < 4; nt++)
                    acc[mt][nt] = mfma16(af[mt], bfr[nt], acc[mt][nt]);
        }
    }
    const int row0 = bm * 128 + (wm << 6);
    const int col0 = bn * 128 + (wn << 6);
    if constexpr (MODE == 0) {
        u16* C = (u16*)Cv;
#pragma unroll
        for (int mt = 0; mt < 4; mt++)
#pragma unroll
            for (int nt = 0; nt < 4; nt++)
#pragma unroll
                for (int r = 0; r < 4; r++)
                    C[(size_t)(row0 + (mt << 4) + (lg << 2) + r) * 512 + col0 + (nt << 4) + lq] =
                        f2bf(acc[mt][nt][r]);
    } else if constexpr (MODE == 3) {
        float* C = (float*)Cv;
        float bv[4];
#pragma unroll
        for (int nt = 0; nt < 4; nt++) bv[nt] = bias[col0 + (nt << 4) + lq];
#pragma unroll
        for (int mt = 0; mt < 4; mt++)
#pragma unroll
            for (int nt = 0; nt < 4; nt++)
#pragma unroll
                for (int r = 0; r < 4; r++)
                    C[(size_t)(row0 + (mt << 4) + (lg << 2) + r) * 512 + col0 + (nt << 4) + lq] =
                        acc[mt][nt][r] + bv[nt];
    } else {
        // LDS-repack fragment-pack epilogue (see round 13 notes).
        __syncthreads();  // K-loop readers done; Ab reusable as repack area (32 KB)
        u16* Cl = Ab;
#pragma unroll
        for (int mt = 0; mt < 4; mt++)
#pragma unroll
            for (int nt = 0; nt < 4; nt++)
#pragma unroll
                for (int r = 0; r < 4; r++) {
                    const int m = row0 + (mt << 4) + (lg << 2) + r;
                    const int d = (col0 + (nt << 4) + lq) & 63;
                    const int kvl = m & 31;
                    const int tl = (m >> 5) & 3;
                    int op;
                    if constexpr (MODE == 1) {
                        op = ((d >> 4) << 9) + ((kvl + (((d >> 3) & 1) << 5)) << 3) + (d & 7);
                    } else {
                        const int lane = (d & 31) + (((kvl >> 3) & 1) << 5);
                        const int fi = ((kvl >> 4) << 1) + (d >> 5);
                        op = (fi << 9) + (lane << 3) + (kvl & 7);
                    }
                    Cl[(((wn << 2) + tl) << 11) + op] = f2bf(acc[mt][nt][r]);
                }
        __syncthreads();
        u16* C = (u16*)Cv;
#pragma unroll
        for (int c = 0; c < 8; c++) {
            const int bhc = ((bm >> 5) << 3) + (bn << 1) + (c >> 2);
            const int Tc = ((bm & 31) << 2) + (c & 3);
            u16* dst = C + ((size_t)((bhc << 7) + Tc) << 11);
            *(u16x8*)(dst + (tid << 3)) = *(const u16x8*)(Cl + (c << 11) + (tid << 3));
        }
    }
}

// fused QKV projection: z=0 -> Q std (K=512), z=1 -> K'-pack (768), z=2 -> V'-pack (768)
__global__ __launch_bounds__(256, 2) void proj_gemm_kernel(
    const u16* __restrict__ xb, const u16* __restrict__ cb, const u16* __restrict__ Wqt,
    const u16* __restrict__ Wkt, const u16* __restrict__ Wvt, u16* __restrict__ Qb,
    u16* __restrict__ Kp, u16* __restrict__ Vp) {
    __shared__ u16 Ab[2][8192];
    __shared__ u16 Bb[2][8192];
    const int z = blockIdx.z;
    if (z == 0)
        gemm_body<0>(&Ab[0][0], &Bb[0][0], xb, Wqt, Qb, nullptr, 512);
    else if (z == 1)
        gemm_body<1>(&Ab[0][0], &Bb[0][0], cb, Wkt, Kp, nullptr, 768);
    else
        gemm_body<2>(&Ab[0][0], &Bb[0][0], cb, Wvt, Vp, nullptr, 768);
}

__global__ __launch_bounds__(256, 2) void out_gemm_kernel(const u16* __restrict__ Ob,
                                                          const u16* __restrict__ Wot,
                                                          float* __restrict__ out,
                                                          const float* __restrict__ bias) {
    __shared__ u16 Ab[2][8192];
    __shared__ u16 Bb[2][8192];
    gemm_body<3>(&Ab[0][0], &Bb[0][0], Ob, Wot, out, bias, 512);
}

// ---------------- flash attention, round 17: row-sum on the matrix pipe ----------------
// Round-16 structure (best: 151.6 us; kv-split x2). Single change: VALU is the critical
// pipe (45% busy vs MFMA 38%); move the row-sum from 15 scalar adds/subtile to
// ls = mfma32(aw, ones, ls) on the matrix pipe (+2 MFMA/subtile), also deleting the
// epilogue shfl_xor. ls lands in O-layout; Lpart store by crow(r,hi) -- layout read by
// merge is unchanged ((wid<<5) == (slot<<6)+(p<<5)).
__global__ __launch_bounds__(256, 3) void attn_kernel(const u16* __restrict__ Qb,
                                                      const u16* __restrict__ Kp,
                                                      const u16* __restrict__ Vp,
                                                      u16* __restrict__ Opart,
                                                      float* __restrict__ Lpart) {
    __shared__ u16 Kl[2][4096];
    __shared__ u16 Vl[2][4096];
    const int tid = threadIdx.x;
    const int w = tid >> 6, l = tid & 63;
    const int lq = l & 31, hi = l >> 5;
    const int bid = blockIdx.x;
    const int swz = ((bid & 7) << 7) + (bid >> 3);  // bijective (1024%8==0), XCD-contiguous
    const int bh = swz >> 6, qtg = (swz >> 1) & 31, kvseg = swz & 1;
    const int qt = (qtg << 2) + w;
    const int wid = (((bh << 7) + qt) << 1) + kvseg;  // slot*2 + kvseg
    const int b = bh >> 3, h = bh & 7;

    // Q B-fragments: qf[s] = Q[qt*32+lq][d = hi*8 + 16s + j]
    const u16* Qp = Qb + (size_t)(b * 4096 + (qt << 5) + lq) * 512 + (h << 6) + (hi << 3);
    s16x8 qf[4];
#pragma unroll
    for (int s = 0; s < 4; s++) qf[s] = ld_frag(Qp + (s << 4));

    // block kv range: 64 tiles starting at T0 = kvseg*64; tile stride 2048 u16 (4KB)
    const u16* Kg = Kp + ((size_t)(bh << 7) + (kvseg << 6)) * 2048;
    const u16* Vg = Vp + ((size_t)(bh << 7) + (kvseg << 6)) * 2048;
    const int gsrc = (w << 9) + (l << 3);  // wave w stages frag w (per-lane global offset)
    const int ldst = w << 9;               // wave-uniform LDS dest (HW adds lane*16)
    const int roff = l << 3;               // per-lane frag read offset (u16)

    f32x16 oacc0 = {}, oacc1 = {}, ls = {};

    s16x8 onesb;
#pragma unroll
    for (int j = 0; j < 8; j++) onesb[j] = 0x3F80;  // bf16 1.0

    // prologue: stage tile pair 0 (tiles 0,1) -> buf 0
    async16(Kg + gsrc, &Kl[0][ldst]);
    async16(Kg + 2048 + gsrc, &Kl[0][2048 + ldst]);
    async16(Vg + gsrc, &Vl[0][ldst]);
    async16(Vg + 2048 + gsrc, &Vl[0][2048 + ldst]);

    // QK^T for one 32-kv subtile with streamed K-frags (2 live)
    auto qk = [&](const u16* Kb_) -> f32x16 {
        f32x16 sacc = {};
        s16x8 fa = ld_frag(Kb_ + roff);
        s16x8 fb = ld_frag(Kb_ + 512 + roff);
        __builtin_amdgcn_s_setprio(1);
        sacc = mfma32(fa, qf[0], sacc);
        fa = ld_frag(Kb_ + 1024 + roff);
        sacc = mfma32(fb, qf[1], sacc);
        fb = ld_frag(Kb_ + 1536 + roff);
        sacc = mfma32(fa, qf[2], sacc);
        sacc = mfma32(fb, qf[3], sacc);
        __builtin_amdgcn_s_setprio(0);
        return sacc;
    };

    // softmax (no-max, exp2 domain) + T12 P->A-fragment repack (row-sum moved to MFMA)
    auto softmax = [&](f32x16& sacc, s16x8 (&aw)[2]) {
#pragma unroll
        for (int r = 0; r < 16; r++) sacc[r] = fexp2(sacc[r]);
#pragma unroll
        for (int sp = 0; sp < 2; sp++) {
            const int base2 = sp << 3;
            unsigned X1 = cvt_pk_bf16(sacc[base2 + 0], sacc[base2 + 1]);
            unsigned Y1 = cvt_pk_bf16(sacc[base2 + 4], sacc[base2 + 5]);
            unsigned X2 = cvt_pk_bf16(sacc[base2 + 2], sacc[base2 + 3]);
            unsigned Y2 = cvt_pk_bf16(sacc[base2 + 6], sacc[base2 + 7]);
            plane32_swap(X1, Y1);
            plane32_swap(X2, Y2);
            u32x4 wv;
            wv[0] = X1; wv[1] = X2; wv[2] = Y1; wv[3] = Y2;
            aw[sp] = __builtin_bit_cast(s16x8, wv);
        }
    };

    // PV + row-sum with streamed V-frags (2 live): O += P@V ; ls += P@ones
    auto pv = [&](const s16x8 (&aw)[2], const u16* Vb_) {
        s16x8 va = ld_frag(Vb_ + roff);
        s16x8 vb = ld_frag(Vb_ + 512 + roff);
        __builtin_amdgcn_s_setprio(1);
        ls = mfma32(aw[0], onesb, ls);
        oacc0 = mfma32(aw[0], va, oacc0);
        va = ld_frag(Vb_ + 1024 + roff);
        oacc1 = mfma32(aw[0], vb, oacc1);
        vb = ld_frag(Vb_ + 1536 + roff);
        ls = mfma32(aw[1], onesb, ls);
        oacc0 = mfma32(aw[1], va, oacc0);
        oacc1 = mfma32(aw[1], vb, oacc1);
        __builtin_amdgcn_s_setprio(0);
    };

    for (int t = 0; t < 32; ++t) {
        const int buf = t & 1;
        __syncthreads();  // drains vmcnt -> staged pair t visible; prev readers done
        if (t + 1 < 32) {
            const size_t base = (size_t)(t + 1) * 4096;
            const int nb = buf ^ 1;
            async16(Kg + base + gsrc, &Kl[nb][ldst]);
            async16(Kg + base + 2048 + gsrc, &Kl[nb][2048 + ldst]);
            async16(Vg + base + gsrc, &Vl[nb][ldst]);
            async16(Vg + base + 2048 + gsrc, &Vl[nb][2048 + ldst]);
        }
        // 2-subtile pipeline: QK0, QK1 | SM0 | PV0 | SM1 | PV1
        f32x16 s0 = qk(&Kl[buf][0]);
        f32x16 s1 = qk(&Kl[buf][2048]);
        s16x8 aw0[2], aw1[2];
        softmax(s0, aw0);
        pv(aw0, &Vl[buf][0]);
        softmax(s1, aw1);
        pv(aw1, &Vl[buf][2048]);
    }

    // store partials in fragment order: Opart[wid][ (dt*16+r)*64 + lane ]
    u16* Ow = Opart + ((size_t)wid << 11);
#pragma unroll
    for (int r = 0; r < 16; r++) Ow[(r << 6) + l] = f2bf(oacc0[r]);
#pragma unroll
    for (int r = 0; r < 16; r++) Ow[((16 + r) << 6) + l] = f2bf(oacc1[r]);
    // denominator: ls[r] = l[q=crow(r,hi)] replicated across lq; store once per (hi,r)
    if (lq == 0) {
#pragma unroll
        for (int r = 0; r < 16; r++)
            Lpart[(wid << 5) + (r & 3) + ((r >> 2) << 3) + (hi << 2)] = ls[r];
    }
}

// ---------------- merge 2 kv-halves: Ob[q][feat] = (O0+O1)/(l0+l1) ----------------
__global__ __launch_bounds__(256) void merge_kernel(const u16* __restrict__ Op,
                                                    const float* __restrict__ Lp,
                                                    u16* __restrict__ Ob) {
    const int g = blockIdx.x * 256 + threadIdx.x;  // oct id, 524,288 total
    const int slot = g >> 8;                       // bh*128 + qt
    const int idx8 = (g & 255) << 3;               // element base within 2048-tile (16B aligned)
    const int dtr = idx8 >> 6;
    const int r = dtr & 15, dt = dtr >> 4;
    const int lane0 = idx8 & 63;                   // multiple of 8; span stays in one 32-half
    const int q = (r & 3) + ((r >> 2) << 3) + ((lane0 >> 5) << 2);
    float lsum = 0.f;
#pragma unroll
    for (int p = 0; p < 2; p++) lsum += Lp[(slot << 6) + (p << 5) + q];
    const float ri = 1.f / lsum;
    float acc[8] = {0.f, 0.f, 0.f, 0.f, 0.f, 0.f, 0.f, 0.f};
#pragma unroll
    for (int p = 0; p < 2; p++) {
        const u16x8 a = *(const u16x8*)(Op + ((size_t)slot << 12) + (p << 11) + idx8);
#pragma unroll
        for (int j = 0; j < 8; j++) acc[j] += bf2f(a[j]);
    }
    u16x8 o;
#pragma unroll
    for (int j = 0; j < 8; j++) o[j] = f2bf(acc[j] * ri);
    const int bh = slot >> 7, qt = slot & 127;
    const int row = ((bh >> 3) << 12) + (qt << 5) + q;
    const int d = (lane0 & 31) + (dt << 5);
    *(u16x8*)(Ob + (size_t)row * 512 + ((bh & 7) << 6) + d) = o;
}

extern "C" void kernel_launch(void* const* d_in, const int* in_sizes, int n_in, void* d_out,
                              int out_size, void* d_ws, size_t ws_size, hipStream_t stream) {
    const float* x = (const float*)d_in[0];    // (2,4096,512)
    const float* ctx = (const float*)d_in[1];  // (2,4096,768)
    const float* Wq = (const float*)d_in[2];   // (512,512)
    const float* Wk = (const float*)d_in[3];   // (768,512)
    const float* Wv = (const float*)d_in[4];   // (768,512)
    const float* Wo = (const float*)d_in[5];   // (512,512)
    const float* bo = (const float*)d_in[6];   // (512,)
    float* out = (float*)d_out;

    char* ws = (char*)d_ws;
    // Phase layout (62,390,272 B total):
    //   [0, 16.8M): Opart  [33.5M, 34.1M): Lpart  -- alias xb/cb, dead before attn
    //   [34.6M, 43M): Qb, reused as Ob by merge (Q dead after attn)
    //   [43M, 51.4M): Kp   [51.4M, 59.8M): Vp   [59.8M, 62.4M): weights
    u16* xb  = (u16*)(ws);
    u16* cb  = (u16*)(ws + 8388608);
    u16* Opart   = (u16*)(ws);                  // 16,777,216 B (2 partials/slot)
    float* Lpart = (float*)(ws + 33554432);     // 524,288 B
    u16* Qb  = (u16*)(ws + 34603008);           // 8,388,608 B
    u16* Ob  = (u16*)(ws + 34603008);           // aliases Qb (dead after attn)
    u16* Kp  = (u16*)(ws + 42991616);           // 8,388,608 B
    u16* Vp  = (u16*)(ws + 51380224);           // 8,388,608 B
    u16* Wqt = (u16*)(ws + 59768832);           // 524,288 B
    u16* Wkt = (u16*)(ws + 60293120);           // 786,432 B
    u16* Wvt = (u16*)(ws + 61079552);           // 786,432 B
    u16* Wot = (u16*)(ws + 61865984);           // 524,288 B -> end 62,390,272

    prep_kernel<<<dim3(6656), dim3(256), 0, stream>>>(x, ctx, Wq, Wk, Wv, Wo, xb, cb, Wqt, Wkt,
                                                      Wvt, Wot);
    proj_gemm_kernel<<<dim3(4, 64, 3), dim3(256), 0, stream>>>(xb, cb, Wqt, Wkt, Wvt, Qb, Kp, Vp);
    attn_kernel<<<dim3(1024), dim3(256), 0, stream>>>(Qb, Kp, Vp, Opart, Lpart);
    merge_kernel<<<dim3(2048), dim3(256), 0, stream>>>(Opart, Lpart, Ob);
    out_gemm_kernel<<<dim3(4, 64), dim3(256), 0, stream>>>(Ob, Wot, out, bo);
}

// Round 18
// 151.431 us; speedup vs baseline: 1.0172x; 1.0172x over previous
//
#include <hip/hip_runtime.h>

typedef unsigned short u16;
typedef __attribute__((ext_vector_type(4))) unsigned short u16x4;
typedef __attribute__((ext_vector_type(8))) unsigned short u16x8;
typedef __attribute__((ext_vector_type(8))) short s16x8;
typedef __attribute__((ext_vector_type(4))) float f32x4;
typedef __attribute__((ext_vector_type(16))) float f32x16;
typedef __attribute__((ext_vector_type(4))) unsigned int u32x4;

#define LOG2E 1.4426950408889634f

__device__ __forceinline__ u16 f2bf(float f) {
    return __builtin_bit_cast(unsigned short, static_cast<__bf16>(f));
}

__device__ __forceinline__ float bf2f(u16 v) {
    return __builtin_bit_cast(float, (unsigned)v << 16);
}

__device__ __forceinline__ float fexp2(float x) {
#if __has_builtin(__builtin_amdgcn_exp2f)
    return __builtin_amdgcn_exp2f(x);
#else
    return exp2f(x);
#endif
}

__device__ __forceinline__ s16x8 ld_frag(const u16* p) {
    return __builtin_bit_cast(s16x8, *reinterpret_cast<const u16x8*>(p));
}

__device__ __forceinline__ f32x4 mfma16(s16x8 a, s16x8 b, f32x4 c) {
    return __builtin_amdgcn_mfma_f32_16x16x32_bf16(a, b, c, 0, 0, 0);
}

__device__ __forceinline__ f32x16 mfma32(s16x8 a, s16x8 b, f32x16 c) {
    return __builtin_amdgcn_mfma_f32_32x32x16_bf16(a, b, c, 0, 0, 0);
}

__device__ __forceinline__ unsigned cvt_pk_bf16(float lo, float hi2) {
    unsigned r;
    asm("v_cvt_pk_bf16_f32 %0, %1, %2" : "=v"(r) : "v"(lo), "v"(hi2));
    return r;
}

__device__ __forceinline__ void plane32_swap(unsigned& x, unsigned& y) {
#if __has_builtin(__builtin_amdgcn_permlane32_swap)
    auto r = __builtin_amdgcn_permlane32_swap(x, y, false, false);
    x = r[0];
    y = r[1];
#else
    asm("v_permlane32_swap_b32 %0, %1" : "+v"(x), "+v"(y));
#endif
}

// async global->LDS, 16B per lane; LDS dest = wave-uniform base + lane*16
__device__ __forceinline__ void async16(const u16* g, u16* lds) {
    __builtin_amdgcn_global_load_lds(
        (__attribute__((address_space(1))) void*)const_cast<u16*>(g),
        (__attribute__((address_space(3))) void*)lds, 16, 0, 0);
}

// ---------------- fused prep: f32->bf16 cvt (x, ctx) + 4 weight transposes ----------------
// blocks [0,5120): cvt; blocks [5120,6656): wtrans (384 per weight, kx in [0,24), ny in [0,16))
__global__ __launch_bounds__(256) void prep_kernel(
    const float* __restrict__ x, const float* __restrict__ ctx, const float* __restrict__ Wq,
    const float* __restrict__ Wk, const float* __restrict__ Wv, const float* __restrict__ Wo,
    u16* __restrict__ xb, u16* __restrict__ cb, u16* __restrict__ Wqt, u16* __restrict__ Wkt,
    u16* __restrict__ Wvt, u16* __restrict__ Wot) {
    __shared__ float t[32][33];
    const int bidx = blockIdx.x;
    const int tid = threadIdx.x;
    if (bidx < 5120) {
        int i = bidx * 256 + tid;  // 1,310,720 total (exact)
        const float* in;
        u16* out;
        int idx;
        if (i < 524288) {
            in = x; out = xb; idx = i;
        } else {
            in = ctx; out = cb; idx = i - 524288;
        }
        const f32x4* p = (const f32x4*)in + ((size_t)idx << 1);
        f32x4 a = p[0], c = p[1];
        u16x8 v;
        v[0] = f2bf(a[0]); v[1] = f2bf(a[1]); v[2] = f2bf(a[2]); v[3] = f2bf(a[3]);
        v[4] = f2bf(c[0]); v[5] = f2bf(c[1]); v[6] = f2bf(c[2]); v[7] = f2bf(c[3]);
        *((u16x8*)out + idx) = v;
    } else {
        const int zb = bidx - 5120;      // 0..1535
        const int z = zb / 384;
        const int rem = zb - z * 384;
        const int kx = rem % 24, ny = rem / 24;
        const float* W;
        u16* Wt;
        int Kd;
        float scale;
        switch (z) {
            case 0: W = Wq; Wt = Wqt; Kd = 512; scale = 1.0f; break;
            case 1: W = Wk; Wt = Wkt; Kd = 768; scale = 0.125f * LOG2E; break;
            case 2: W = Wv; Wt = Wvt; Kd = 768; scale = 1.0f; break;
            default: W = Wo; Wt = Wot; Kd = 512; scale = 1.0f; break;
        }
        const int k0 = kx << 5, n0 = ny << 5;
        if (k0 >= Kd) return;
        const int tx = tid & 31, ty = tid >> 5;
#pragma unroll
        for (int i = 0; i < 32; i += 8)
            t[ty + i][tx] = W[(size_t)(k0 + ty + i) * 512 + n0 + tx] * scale;
        __syncthreads();
#pragma unroll
        for (int i = 0; i < 32; i += 8)
            Wt[(size_t)(n0 + ty + i) * Kd + k0 + tx] = f2bf(t[tx][ty + i]);
    }
}

// ---------------- 128x128 bf16 GEMM body: C = A[M][K] @ Bt[512][K]^T ----------------
// MODE 0: bf16 std [m][512]; MODE 1: K fragment-pack; MODE 2: V fragment-pack;
// MODE 3: f32 std + bias.
// MODE 1/2 epilogue: LDS repack (into dead Ab) -> 8 coalesced 4KB chunk copies.
template <int MODE>
__device__ __forceinline__ void gemm_body(u16* __restrict__ Ab, u16* __restrict__ Bb,
                                          const u16* __restrict__ A, const u16* __restrict__ Bt,
                                          void* __restrict__ Cv, const float* __restrict__ bias,
                                          int K) {
    const int tid = threadIdx.x;
    const int w = tid >> 6, l = tid & 63;
    const int lg = l >> 4, lq = l & 15;
    const int wm = w >> 1, wn = w & 1;
    const int bm = blockIdx.y, bn = blockIdx.x;
    const int KT = K >> 6;

    f32x4 acc[4][4];
#pragma unroll
    for (int i = 0; i < 4; i++)
#pragma unroll
        for (int j = 0; j < 4; j++) acc[i][j] = (f32x4){0.f, 0.f, 0.f, 0.f};

    const u16* Ag0 = A + (size_t)bm * 128 * K;
    const u16* Bg0 = Bt + (size_t)bn * 128 * K;
    const int srow = l >> 3, scol = (l & 7) << 3;

    auto stage = [&](int kt, int buf) {
#pragma unroll
        for (int i = 0; i < 4; i++) {
            const int c = (w << 2) + i;
            const int row = (c << 3) + srow;
            async16(Ag0 + (size_t)row * K + kt * 64 + scol, Ab + (buf << 13) + (c << 9));
            async16(Bg0 + (size_t)row * K + kt * 64 + scol, Bb + (buf << 13) + (c << 9));
        }
    };

    stage(0, 0);
    for (int kt = 0; kt < KT; ++kt) {
        __syncthreads();
        if (kt + 1 < KT) stage(kt + 1, (kt + 1) & 1);
        const u16* As = Ab + ((kt & 1) << 13);
        const u16* Bs = Bb + ((kt & 1) << 13);
#pragma unroll
        for (int s = 0; s < 2; s++) {
            s16x8 af[4], bfr[4];
#pragma unroll
            for (int mt = 0; mt < 4; mt++)
                af[mt] = ld_frag(As + ((wm << 6) + (mt << 4) + lq) * 64 + (s << 5) + (lg << 3));
#pragma unroll
            for (int nt = 0; nt < 4; nt++)
                bfr[nt] = ld_frag(Bs + ((wn << 6) + (nt << 4) + lq) * 64 + (s << 5) + (lg << 3));
#pragma unroll
            for (int mt = 0; mt < 4; mt++)
#pragma unroll
                for (int nt = 0; nt < 4; nt++)
                    acc[mt][nt] = mfma16(af[mt], bfr[nt], acc[mt][nt]);
        }
    }
    const int row0 = bm * 128 + (wm << 6);
    const int col0 = bn * 128 + (wn << 6);
    if constexpr (MODE == 0) {
        u16* C = (u16*)Cv;
#pragma unroll
        for (int mt = 0; mt < 4; mt++)
#pragma unroll
            for (int nt = 0; nt < 4; nt++)
#pragma unroll
                for (int r = 0; r < 4; r++)
                    C[(size_t)(row0 + (mt << 4) + (lg << 2) + r) * 512 + col0 + (nt << 4) + lq] =
                        f2bf(acc[mt][nt][r]);
    } else if constexpr (MODE == 3) {
        float* C = (float*)Cv;
        float bv[4];
#pragma unroll
        for (int nt = 0; nt < 4; nt++) bv[nt] = bias[col0 + (nt << 4) + lq];
#pragma unroll
        for (int mt = 0; mt < 4; mt++)
#pragma unroll
            for (int nt = 0; nt < 4; nt++)
#pragma unroll
                for (int r = 0; r < 4; r++)
                    C[(size_t)(row0 + (mt << 4) + (lg << 2) + r) * 512 + col0 + (nt << 4) + lq] =
                        acc[mt][nt][r] + bv[nt];
    } else {
        // LDS-repack fragment-pack epilogue (see round 13 notes).
        __syncthreads();  // K-loop readers done; Ab reusable as repack area (32 KB)
        u16* Cl = Ab;
#pragma unroll
        for (int mt = 0; mt < 4; mt++)
#pragma unroll
            for (int nt = 0; nt < 4; nt++)
#pragma unroll
                for (int r = 0; r < 4; r++) {
                    const int m = row0 + (mt << 4) + (lg << 2) + r;
                    const int d = (col0 + (nt << 4) + lq) & 63;
                    const int kvl = m & 31;
                    const int tl = (m >> 5) & 3;
                    int op;
                    if constexpr (MODE == 1) {
                        op = ((d >> 4) << 9) + ((kvl + (((d >> 3) & 1) << 5)) << 3) + (d & 7);
                    } else {
                        const int lane = (d & 31) + (((kvl >> 3) & 1) << 5);
                        const int fi = ((kvl >> 4) << 1) + (d >> 5);
                        op = (fi << 9) + (lane << 3) + (kvl & 7);
                    }
                    Cl[(((wn << 2) + tl) << 11) + op] = f2bf(acc[mt][nt][r]);
                }
        __syncthreads();
        u16* C = (u16*)Cv;
#pragma unroll
        for (int c = 0; c < 8; c++) {
            const int bhc = ((bm >> 5) << 3) + (bn << 1) + (c >> 2);
            const int Tc = ((bm & 31) << 2) + (c & 3);
            u16* dst = C + ((size_t)((bhc << 7) + Tc) << 11);
            *(u16x8*)(dst + (tid << 3)) = *(const u16x8*)(Cl + (c << 11) + (tid << 3));
        }
    }
}

// fused QKV projection: z=0 -> Q std (K=512), z=1 -> K'-pack (768), z=2 -> V'-pack (768)
__global__ __launch_bounds__(256, 2) void proj_gemm_kernel(
    const u16* __restrict__ xb, const u16* __restrict__ cb, const u16* __restrict__ Wqt,
    const u16* __restrict__ Wkt, const u16* __restrict__ Wvt, u16* __restrict__ Qb,
    u16* __restrict__ Kp, u16* __restrict__ Vp) {
    __shared__ u16 Ab[2][8192];
    __shared__ u16 Bb[2][8192];
    const int z = blockIdx.z;
    if (z == 0)
        gemm_body<0>(&Ab[0][0], &Bb[0][0], xb, Wqt, Qb, nullptr, 512);
    else if (z == 1)
        gemm_body<1>(&Ab[0][0], &Bb[0][0], cb, Wkt, Kp, nullptr, 768);
    else
        gemm_body<2>(&Ab[0][0], &Bb[0][0], cb, Wvt, Vp, nullptr, 768);
}

__global__ __launch_bounds__(256, 2) void out_gemm_kernel(const u16* __restrict__ Ob,
                                                          const u16* __restrict__ Wot,
                                                          float* __restrict__ out,
                                                          const float* __restrict__ bias) {
    __shared__ u16 Ab[2][8192];
    __shared__ u16 Bb[2][8192];
    gemm_body<3>(&Ab[0][0], &Bb[0][0], Ob, Wot, out, bias, 512);
}

// ---------------- flash attention (round-16 optimum): kv-split x2 ----------------
// Plateau structure: LDS-shared KV (4 waves/block), fragment-packed K'/V' (linear
// global_load_lds staging, conflict-free b128 reads), 2-subtile pipeline, no-max exp2
// softmax with scalar row-sum (r17 proved MFMA row-sum regresses), kv-split x2 + merge.
// Proven plateau at ~81.5 us across: waves x1.5/x2 (r9/r13), barriers /2 (r11),
// reg-cap (r12), SW-pipeline (r14), VALU->MFMA offload (r17).
__global__ __launch_bounds__(256, 3) void attn_kernel(const u16* __restrict__ Qb,
                                                      const u16* __restrict__ Kp,
                                                      const u16* __restrict__ Vp,
                                                      u16* __restrict__ Opart,
                                                      float* __restrict__ Lpart) {
    __shared__ u16 Kl[2][4096];
    __shared__ u16 Vl[2][4096];
    const int tid = threadIdx.x;
    const int w = tid >> 6, l = tid & 63;
    const int lq = l & 31, hi = l >> 5;
    const int bid = blockIdx.x;
    const int swz = ((bid & 7) << 7) + (bid >> 3);  // bijective (1024%8==0), XCD-contiguous
    const int bh = swz >> 6, qtg = (swz >> 1) & 31, kvseg = swz & 1;
    const int qt = (qtg << 2) + w;
    const int wid = (((bh << 7) + qt) << 1) + kvseg;  // slot*2 + kvseg
    const int b = bh >> 3, h = bh & 7;

    // Q B-fragments: qf[s] = Q[qt*32+lq][d = hi*8 + 16s + j]
    const u16* Qp = Qb + (size_t)(b * 4096 + (qt << 5) + lq) * 512 + (h << 6) + (hi << 3);
    s16x8 qf[4];
#pragma unroll
    for (int s = 0; s < 4; s++) qf[s] = ld_frag(Qp + (s << 4));

    // block kv range: 64 tiles starting at T0 = kvseg*64; tile stride 2048 u16 (4KB)
    const u16* Kg = Kp + ((size_t)(bh << 7) + (kvseg << 6)) * 2048;
    const u16* Vg = Vp + ((size_t)(bh << 7) + (kvseg << 6)) * 2048;
    const int gsrc = (w << 9) + (l << 3);  // wave w stages frag w (per-lane global offset)
    const int ldst = w << 9;               // wave-uniform LDS dest (HW adds lane*16)
    const int roff = l << 3;               // per-lane frag read offset (u16)

    f32x16 oacc0 = {}, oacc1 = {};
    float rs = 0.f;

    // prologue: stage tile pair 0 (tiles 0,1) -> buf 0
    async16(Kg + gsrc, &Kl[0][ldst]);
    async16(Kg + 2048 + gsrc, &Kl[0][2048 + ldst]);
    async16(Vg + gsrc, &Vl[0][ldst]);
    async16(Vg + 2048 + gsrc, &Vl[0][2048 + ldst]);

    // QK^T for one 32-kv subtile with streamed K-frags (2 live)
    auto qk = [&](const u16* Kb_) -> f32x16 {
        f32x16 sacc = {};
        s16x8 fa = ld_frag(Kb_ + roff);
        s16x8 fb = ld_frag(Kb_ + 512 + roff);
        __builtin_amdgcn_s_setprio(1);
        sacc = mfma32(fa, qf[0], sacc);
        fa = ld_frag(Kb_ + 1024 + roff);
        sacc = mfma32(fb, qf[1], sacc);
        fb = ld_frag(Kb_ + 1536 + roff);
        sacc = mfma32(fa, qf[2], sacc);
        sacc = mfma32(fb, qf[3], sacc);
        __builtin_amdgcn_s_setprio(0);
        return sacc;
    };

    // softmax (no-max, exp2 domain) + row-sum + T12 P->A-fragment repack
    auto softmax = [&](f32x16& sacc, s16x8 (&aw)[2]) {
#pragma unroll
        for (int r = 0; r < 16; r++) sacc[r] = fexp2(sacc[r]);
        {
            float t0 = (sacc[0] + sacc[1]) + (sacc[2] + sacc[3]);
            float t1 = (sacc[4] + sacc[5]) + (sacc[6] + sacc[7]);
            float t2 = (sacc[8] + sacc[9]) + (sacc[10] + sacc[11]);
            float t3 = (sacc[12] + sacc[13]) + (sacc[14] + sacc[15]);
            rs += (t0 + t1) + (t2 + t3);
        }
#pragma unroll
        for (int sp = 0; sp < 2; sp++) {
            const int base2 = sp << 3;
            unsigned X1 = cvt_pk_bf16(sacc[base2 + 0], sacc[base2 + 1]);
            unsigned Y1 = cvt_pk_bf16(sacc[base2 + 4], sacc[base2 + 5]);
            unsigned X2 = cvt_pk_bf16(sacc[base2 + 2], sacc[base2 + 3]);
            unsigned Y2 = cvt_pk_bf16(sacc[base2 + 6], sacc[base2 + 7]);
            plane32_swap(X1, Y1);
            plane32_swap(X2, Y2);
            u32x4 wv;
            wv[0] = X1; wv[1] = X2; wv[2] = Y1; wv[3] = Y2;
            aw[sp] = __builtin_bit_cast(s16x8, wv);
        }
    };

    // PV with streamed V-frags (2 live)
    auto pv = [&](const s16x8 (&aw)[2], const u16* Vb_) {
        s16x8 va = ld_frag(Vb_ + roff);
        s16x8 vb = ld_frag(Vb_ + 512 + roff);
        __builtin_amdgcn_s_setprio(1);
        oacc0 = mfma32(aw[0], va, oacc0);
        va = ld_frag(Vb_ + 1024 + roff);
        oacc1 = mfma32(aw[0], vb, oacc1);
        vb = ld_frag(Vb_ + 1536 + roff);
        oacc0 = mfma32(aw[1], va, oacc0);
        oacc1 = mfma32(aw[1], vb, oacc1);
        __builtin_amdgcn_s_setprio(0);
    };

    for (int t = 0; t < 32; ++t) {
        const int buf = t & 1;
        __syncthreads();  // drains vmcnt -> staged pair t visible; prev readers done
        if (t + 1 < 32) {
            const size_t base = (size_t)(t + 1) * 4096;
            const int nb = buf ^ 1;
            async16(Kg + base + gsrc, &Kl[nb][ldst]);
            async16(Kg + base + 2048 + gsrc, &Kl[nb][2048 + ldst]);
            async16(Vg + base + gsrc, &Vl[nb][ldst]);
            async16(Vg + base + 2048 + gsrc, &Vl[nb][2048 + ldst]);
        }
        // 2-subtile pipeline: QK0, QK1 | SM0 | PV0 | SM1 | PV1
        f32x16 s0 = qk(&Kl[buf][0]);
        f32x16 s1 = qk(&Kl[buf][2048]);
        s16x8 aw0[2], aw1[2];
        softmax(s0, aw0);
        pv(aw0, &Vl[buf][0]);
        softmax(s1, aw1);
        pv(aw1, &Vl[buf][2048]);
    }

    // store partials in fragment order: Opart[wid][ (dt*16+r)*64 + lane ]
    u16* Ow = Opart + ((size_t)wid << 11);
#pragma unroll
    for (int r = 0; r < 16; r++) Ow[(r << 6) + l] = f2bf(oacc0[r]);
#pragma unroll
    for (int r = 0; r < 16; r++) Ow[((16 + r) << 6) + l] = f2bf(oacc1[r]);
    // denominator: lane pair (l, l+32) both hold q=lq partial; sum and store once
    rs += __shfl_xor(rs, 32);
    if (l < 32) Lpart[(wid << 5) + l] = rs;
}

// ---------------- merge 2 kv-halves: Ob[q][feat] = (O0+O1)/(l0+l1) ----------------
__global__ __launch_bounds__(256) void merge_kernel(const u16* __restrict__ Op,
                                                    const float* __restrict__ Lp,
                                                    u16* __restrict__ Ob) {
    const int g = blockIdx.x * 256 + threadIdx.x;  // oct id, 524,288 total
    const int slot = g >> 8;                       // bh*128 + qt
    const int idx8 = (g & 255) << 3;               // element base within 2048-tile (16B aligned)
    const int dtr = idx8 >> 6;
    const int r = dtr & 15, dt = dtr >> 4;
    const int lane0 = idx8 & 63;                   // multiple of 8; span stays in one 32-half
    const int q = (r & 3) + ((r >> 2) << 3) + ((lane0 >> 5) << 2);
    float lsum = 0.f;
#pragma unroll
    for (int p = 0; p < 2; p++) lsum += Lp[(slot << 6) + (p << 5) + q];
    const float ri = 1.f / lsum;
    float acc[8] = {0.f, 0.f, 0.f, 0.f, 0.f, 0.f, 0.f, 0.f};
#pragma unroll
    for (int p = 0; p < 2; p++) {
        const u16x8 a = *(const u16x8*)(Op + ((size_t)slot << 12) + (p << 11) + idx8);
#pragma unroll
        for (int j = 0; j < 8; j++) acc[j] += bf2f(a[j]);
    }
    u16x8 o;
#pragma unroll
    for (int j = 0; j < 8; j++) o[j] = f2bf(acc[j] * ri);
    const int bh = slot >> 7, qt = slot & 127;
    const int row = ((bh >> 3) << 12) + (qt << 5) + q;
    const int d = (lane0 & 31) + (dt << 5);
    *(u16x8*)(Ob + (size_t)row * 512 + ((bh & 7) << 6) + d) = o;
}

extern "C" void kernel_launch(void* const* d_in, const int* in_sizes, int n_in, void* d_out,
                              int out_size, void* d_ws, size_t ws_size, hipStream_t stream) {
    const float* x = (const float*)d_in[0];    // (2,4096,512)
    const float* ctx = (const float*)d_in[1];  // (2,4096,768)
    const float* Wq = (const float*)d_in[2];   // (512,512)
    const float* Wk = (const float*)d_in[3];   // (768,512)
    const float* Wv = (const float*)d_in[4];   // (768,512)
    const float* Wo = (const float*)d_in[5];   // (512,512)
    const float* bo = (const float*)d_in[6];   // (512,)
    float* out = (float*)d_out;

    char* ws = (char*)d_ws;
    // Phase layout (62,390,272 B total):
    //   [0, 16.8M): Opart  [33.5M, 34.1M): Lpart  -- alias xb/cb, dead before attn
    //   [34.6M, 43M): Qb, reused as Ob by merge (Q dead after attn)
    //   [43M, 51.4M): Kp   [51.4M, 59.8M): Vp   [59.8M, 62.4M): weights
    u16* xb  = (u16*)(ws);
    u16* cb  = (u16*)(ws + 8388608);
    u16* Opart   = (u16*)(ws);                  // 16,777,216 B (2 partials/slot)
    float* Lpart = (float*)(ws + 33554432);     // 524,288 B
    u16* Qb  = (u16*)(ws + 34603008);           // 8,388,608 B
    u16* Ob  = (u16*)(ws + 34603008);           // aliases Qb (dead after attn)
    u16* Kp  = (u16*)(ws + 42991616);           // 8,388,608 B
    u16* Vp  = (u16*)(ws + 51380224);           // 8,388,608 B
    u16* Wqt = (u16*)(ws + 59768832);           // 524,288 B
    u16* Wkt = (u16*)(ws + 60293120);           // 786,432 B
    u16* Wvt = (u16*)(ws + 61079552);           // 786,432 B
    u16* Wot = (u16*)(ws + 61865984);           // 524,288 B -> end 62,390,272

    prep_kernel<<<dim3(6656), dim3(256), 0, stream>>>(x, ctx, Wq, Wk, Wv, Wo, xb, cb, Wqt, Wkt,
                                                      Wvt, Wot);
    proj_gemm_kernel<<<dim3(4, 64, 3), dim3(256), 0, stream>>>(xb, cb, Wqt, Wkt, Wvt, Qb, Kp, Vp);
    attn_kernel<<<dim3(1024), dim3(256), 0, stream>>>(Qb, Kp, Vp, Opart, Lpart);
    merge_kernel<<<dim3(2048), dim3(256), 0, stream>>>(Opart, Lpart, Ob);
    out_gemm_kernel<<<dim3(4, 64), dim3(256), 0, stream>>>(Ob, Wot, out, bo);
}